// Round 2
// baseline (454.515 us; speedup 1.0000x reference)
//
#include <hip/hip_runtime.h>
#include <stdint.h>

#define N_ROWS 65536
#define CIN 256
#define COUT 128

typedef __bf16 bf16x8 __attribute__((ext_vector_type(8)));
typedef float f32x4 __attribute__((ext_vector_type(4)));
typedef unsigned short u16;
typedef unsigned int u32;

// truncate fp32 -> bf16 (bitwise). BN stats are computed from the SAME
// truncated values, so the systematic truncation bias cancels in normalize.
__device__ __forceinline__ float truncbf(float f) {
  u32 x = __builtin_bit_cast(u32, f) & 0xFFFF0000u;
  return __builtin_bit_cast(float, x);
}
// pack trunc-bf16(hi) into one dword: {hi16(b), hi16(a)} -> (bf(b)<<16)|bf(a)
__device__ __forceinline__ u32 packbf(float a, float b) {
  return __builtin_amdgcn_perm(__builtin_bit_cast(u32, b),
                               __builtin_bit_cast(u32, a), 0x07060302u);
}

// async global->LDS, 16B/lane; LDS dest = wave-uniform base + lane*16.
__device__ __forceinline__ void async_ld16(const float* g, float* l) {
  __builtin_amdgcn_global_load_lds((const __attribute__((address_space(1))) u32*)g,
                                   (__attribute__((address_space(3))) u32*)l,
                                   16, 0, 0);
}

// ---------------------------------------------------------------------------
// Kernel 1: partial Gram G_b = x~^T x~ over 512-row slices + colsum(x~).
// x fp32 -> trunc bf16, staged TRANSPOSED in LDS (xT[c][k], pitch 18 dwords).
// Partials (fp32, symmetric -> layout-swap-safe) go to d_out scratch.
// ---------------------------------------------------------------------------
__global__ __launch_bounds__(512, 2) void gram_partial(const float* __restrict__ x,
                                                       float* __restrict__ part,
                                                       float* __restrict__ colsum) {
  __shared__ u32 xT[256 * 18];        // 18KB: ch-major, k-pairs packed in dwords
  const int tid = threadIdx.x, lane = tid & 63;
  const int w = tid >> 6;
  const int wm = w >> 2, wn = w & 3;  // wave tile: 128 (m) x 64 (n)
  const int q = lane >> 4, r = lane & 15;
  const int row0 = blockIdx.x * 512;
  const int cpair = tid & 127, c0 = cpair * 2;
  const int npb = tid >> 7;           // 0..3

  f32x4 acc[8][4];
  #pragma unroll
  for (int i = 0; i < 8; ++i)
    #pragma unroll
    for (int j = 0; j < 4; ++j) acc[i][j] = (f32x4){0.f, 0.f, 0.f, 0.f};
  float cs0 = 0.f, cs1 = 0.f;

  for (int ch = 0; ch < 16; ++ch) {
    const int r0 = row0 + ch * 32;
    #pragma unroll
    for (int i = 0; i < 4; ++i) {
      int np = npb + i * 4;           // 0..15 row-pairs
      int n0 = r0 + np * 2;
      float2 g0 = *(const float2*)&x[(size_t)n0 * CIN + c0];
      float2 g1 = *(const float2*)&x[(size_t)(n0 + 1) * CIN + c0];
      xT[18 * c0 + np] = packbf(g0.x, g1.x);
      xT[18 * (c0 + 1) + np] = packbf(g0.y, g1.y);
      cs0 += truncbf(g0.x) + truncbf(g1.x);
      cs1 += truncbf(g0.y) + truncbf(g1.y);
    }
    __syncthreads();
    bf16x8 af[8], bfr[4];
    #pragma unroll
    for (int mt = 0; mt < 8; ++mt) {
      int c = wm * 128 + mt * 16 + r;
      union { u32 d[4]; bf16x8 v; } t;
      const u32* p = &xT[18 * c + 4 * q];
      t.d[0] = p[0]; t.d[1] = p[1]; t.d[2] = p[2]; t.d[3] = p[3];
      af[mt] = t.v;
    }
    #pragma unroll
    for (int nt = 0; nt < 4; ++nt) {
      int c = wn * 64 + nt * 16 + r;
      union { u32 d[4]; bf16x8 v; } t;
      const u32* p = &xT[18 * c + 4 * q];
      t.d[0] = p[0]; t.d[1] = p[1]; t.d[2] = p[2]; t.d[3] = p[3];
      bfr[nt] = t.v;
    }
    #pragma unroll
    for (int mt = 0; mt < 8; ++mt)
      #pragma unroll
      for (int nt = 0; nt < 4; ++nt)
        acc[mt][nt] = __builtin_amdgcn_mfma_f32_16x16x32_bf16(af[mt], bfr[nt], acc[mt][nt], 0, 0, 0);
    __syncthreads();
  }

  float* pb = part + (size_t)blockIdx.x * 65536;
  #pragma unroll
  for (int mt = 0; mt < 8; ++mt)
    #pragma unroll
    for (int nt = 0; nt < 4; ++nt)
      #pragma unroll
      for (int i = 0; i < 4; ++i) {
        int row = wm * 128 + mt * 16 + q * 4 + i;
        int col = wn * 64 + nt * 16 + r;
        pb[row * 256 + col] = acc[mt][nt][i];
      }
  atomicAdd(&colsum[c0], cs0);
  atomicAdd(&colsum[c0 + 1], cs1);
}

// ---------------------------------------------------------------------------
// Kernel 2: reduce 128 partial Grams -> G (256x256 fp32)
// ---------------------------------------------------------------------------
__global__ void gram_reduce(const float* __restrict__ part, float* __restrict__ G) {
  int idx = (blockIdx.x * 256 + threadIdx.x) * 4;
  float s0 = 0.f, s1 = 0.f, s2 = 0.f, s3 = 0.f;
  for (int b = 0; b < 128; ++b) {
    float4 v = *(const float4*)(part + (size_t)b * 65536 + idx);
    s0 += v.x; s1 += v.y; s2 += v.z; s3 += v.w;
  }
  float4 o; o.x = s0; o.y = s1; o.z = s2; o.w = s3;
  *(float4*)(G + idx) = o;
}

// ---------------------------------------------------------------------------
// Kernel 3: BN scale/bias per channel d from quadratic form (uses trunc-W,
// matching the GEMM's operands exactly).
// ---------------------------------------------------------------------------
__global__ __launch_bounds__(256) void stats_kernel(const float* __restrict__ G,
                                                    const float* __restrict__ colsum,
                                                    const float* __restrict__ W,
                                                    const float* __restrict__ gamma,
                                                    const float* __restrict__ beta,
                                                    float* __restrict__ scale,
                                                    float* __restrict__ bias) {
  const int d = blockIdx.x;
  const int t = threadIdx.x;
  __shared__ float wv[256][8];
  __shared__ float rr[16];
  float wt[8];
  #pragma unroll
  for (int k = 0; k < 8; ++k) wt[k] = truncbf(W[((size_t)k * CIN + t) * COUT + d]);
  #pragma unroll
  for (int k = 0; k < 8; ++k) wv[t][k] = wt[k];
  __syncthreads();

  float q = 0.f;
  for (int j = 0; j < 256; ++j) {
    float g = G[j * 256 + t];
    float dot = 0.f;
    #pragma unroll
    for (int k = 0; k < 8; ++k) dot += wv[j][k] * wt[k];
    q += g * dot;
  }
  float wsum = 0.f;
  #pragma unroll
  for (int k = 0; k < 8; ++k) wsum += wt[k];
  float m = colsum[t] * wsum;

  #pragma unroll
  for (int off = 32; off; off >>= 1) {
    q += __shfl_down(q, off, 64);
    m += __shfl_down(m, off, 64);
  }
  int wid = t >> 6;
  if ((t & 63) == 0) { rr[wid] = q; rr[wid + 8] = m; }
  __syncthreads();
  if (t == 0) {
    float qt = rr[0] + rr[1] + rr[2] + rr[3];
    float mn = rr[8] + rr[9] + rr[10] + rr[11];
    const float invM = 1.f / 524288.f;
    float mean = mn * invM;
    float var = qt * invM - mean * mean;
    float s = gamma[d] * rsqrtf(var + 1e-5f);
    scale[d] = s;
    bias[d] = beta[d] - mean * s;
  }
}

// ---------------------------------------------------------------------------
// Kernel 4: W fp32 [k][c][d] -> Wt bf16 [(k*8+cb)][d][ci] (B-fragment layout)
// ---------------------------------------------------------------------------
__global__ void wtrans_kernel(const float* __restrict__ W, u16* __restrict__ Wt) {
  __shared__ u16 tile[32][128];
  const int blk = blockIdx.x, t = threadIdx.x;
  const int k = blk >> 3, cb = blk & 7;
  #pragma unroll
  for (int i = 0; i < 4; ++i) {
    int u = t + i * 256;
    int ci = u >> 5, d4 = (u & 31) * 4;
    float4 f = *(const float4*)&W[((size_t)k * CIN + cb * 32 + ci) * COUT + d4];
    uint2 p; p.x = packbf(f.x, f.y); p.y = packbf(f.z, f.w);
    *(uint2*)&tile[ci][d4] = p;
  }
  __syncthreads();
  #pragma unroll
  for (int i = 0; i < 2; ++i) {
    int v = t + i * 256;
    int d = v >> 2, c0 = (v & 3) * 8;
    union { u16 s[8]; uint4 u4; } p;
    #pragma unroll
    for (int j = 0; j < 8; ++j) p.s[j] = tile[c0 + j][d];
    *(uint4*)&Wt[((size_t)blk * 128 + d) * 32 + c0] = p.u4;
  }
}

// ---------------------------------------------------------------------------
// Kernel 5: GEMM (x~ @ W~[k]) + fused BN/ReLU. 128x128 tile per block.
// A: fp32 staged via global_load_lds w=16 with XOR-swizzled 16B units
//    (kills the 16-way pitch-32 conflict -> 2-way free), trunc->bf16 on
//    fragment load via v_perm. B: bf16 from Wt, double-buffered in regs.
// ---------------------------------------------------------------------------
__global__ __launch_bounds__(256, 2) void gemm_kernel(const float* __restrict__ x,
                                                      const u16* __restrict__ Wt,
                                                      const float* __restrict__ scale,
                                                      const float* __restrict__ bias,
                                                      float* __restrict__ out) {
  __shared__ float As[4096];          // 16KB A-tile; reused as epilogue tile
  const int tid = threadIdx.x, lane = tid & 63;
  const int w = tid >> 6, wr = w >> 1, wc = w & 1;
  const int q = lane >> 4, r = lane & 15;
  const int k = blockIdx.x & 7;
  const int m0 = (blockIdx.x >> 3) * 128;

  const u16* wbase = Wt + (size_t)k * 8 * 4096;
  const int boff = (wc * 64 + r) * 32 + q * 8;   // + nt*16*32 + cb*4096

  bf16x8 bcur[4], bnext[4];
  #pragma unroll
  for (int nt = 0; nt < 4; ++nt)
    bcur[nt] = *(const bf16x8*)&wbase[boff + nt * 512];

  f32x4 acc[4][4];
  #pragma unroll
  for (int i = 0; i < 4; ++i)
    #pragma unroll
    for (int j = 0; j < 4; ++j) acc[i][j] = (f32x4){0.f, 0.f, 0.f, 0.f};

  for (int cb = 0; cb < 8; ++cb) {
    #pragma unroll
    for (int i = 0; i < 4; ++i) {
      int u = tid + i * 256;          // 1024 units of 16B = 128 rows x 8 segs
      int row = u >> 3;
      int s = (u & 7) ^ (row & 7);    // XOR swizzle
      const float* g = x + (size_t)(m0 + row) * CIN + cb * 32 + s * 4;
      float* l = As + (w * 64 + i * 256) * 4;    // wave-uniform base
      async_ld16(g, l);
    }
    if (cb < 7) {
      #pragma unroll
      for (int nt = 0; nt < 4; ++nt)
        bnext[nt] = *(const bf16x8*)&wbase[(cb + 1) * 4096 + boff + nt * 512];
    }
    __syncthreads();
    bf16x8 af[4];
    #pragma unroll
    for (int mt = 0; mt < 4; ++mt) {
      int row = wr * 64 + mt * 16 + r;
      union { u32 d[4]; bf16x8 v; } t;
      #pragma unroll
      for (int b = 0; b < 2; ++b) {
        int unit = row * 8 + ((2 * q + b) ^ (row & 7));
        float4 f = *(const float4*)&As[unit * 4];
        t.d[b * 2 + 0] = packbf(f.x, f.y);
        t.d[b * 2 + 1] = packbf(f.z, f.w);
      }
      af[mt] = t.v;
    }
    #pragma unroll
    for (int mt = 0; mt < 4; ++mt)
      #pragma unroll
      for (int nt = 0; nt < 4; ++nt)
        acc[mt][nt] = __builtin_amdgcn_mfma_f32_16x16x32_bf16(af[mt], bcur[nt], acc[mt][nt], 0, 0, 0);
    __syncthreads();
    if (cb < 7) {
      #pragma unroll
      for (int nt = 0; nt < 4; ++nt) bcur[nt] = bnext[nt];
    }
  }

  float sv[4], bv[4];
  #pragma unroll
  for (int nt = 0; nt < 4; ++nt) {
    int col = wc * 64 + nt * 16 + r;
    sv[nt] = scale[col]; bv[nt] = bias[col];
  }
  #pragma unroll
  for (int mt = 0; mt < 4; ++mt) {
    if (mt) __syncthreads();
    #pragma unroll
    for (int nt = 0; nt < 4; ++nt)
      #pragma unroll
      for (int i = 0; i < 4; ++i) {
        int rl = wr * 16 + q * 4 + i;           // 32-row sub-tile
        int col = wc * 64 + nt * 16 + r;
        float y = acc[mt][nt][i] * sv[nt] + bv[nt];
        y = y > 0.f ? y : 0.f;
        As[rl * 128 + col] = y;
      }
    __syncthreads();
    #pragma unroll
    for (int i = 0; i < 4; ++i) {
      int u = tid + i * 256;
      int rl = u >> 5, off = (u & 31) * 4;
      int grow = m0 + (rl >> 4) * 64 + mt * 16 + (rl & 15);
      *(float4*)&out[((size_t)k * N_ROWS + grow) * COUT + off] =
          *(const float4*)&As[rl * 128 + off];
    }
  }
}

extern "C" void kernel_launch(void* const* d_in, const int* in_sizes, int n_in,
                              void* d_out, int out_size, void* d_ws, size_t ws_size,
                              hipStream_t stream) {
  const float* x = (const float*)d_in[0];
  const float* W = (const float*)d_in[1];
  const float* gamma = (const float*)d_in[2];
  const float* beta = (const float*)d_in[3];
  float* out = (float*)d_out;

  float* ws = (float*)d_ws;
  float* G = ws;                       // 65536 f32 (256KB)
  float* colsum = ws + 65536;          // 256
  float* scale = ws + 65792;           // 128
  float* bias = ws + 65920;            // 128
  u16* Wt = (u16*)(ws + 66048);        // 262144 bf16 (512KB)

  // Gram partials staged in d_out (33.5MB of 256MB) — fully overwritten later.
  float* part = (float*)d_out;

  hipMemsetAsync(colsum, 0, 256 * sizeof(float), stream);
  gram_partial<<<128, 512, 0, stream>>>(x, part, colsum);
  gram_reduce<<<64, 256, 0, stream>>>(part, G);
  stats_kernel<<<128, 256, 0, stream>>>(G, colsum, W, gamma, beta, scale, bias);
  wtrans_kernel<<<64, 256, 0, stream>>>(W, Wt);
  gemm_kernel<<<4096, 256, 0, stream>>>(x, Wt, scale, bias, out);
}

// Round 3
// 393.100 us; speedup vs baseline: 1.1562x; 1.1562x over previous
//
#include <hip/hip_runtime.h>
#include <stdint.h>

#define N_ROWS 65536
#define CIN 256
#define COUT 128

typedef __bf16 bf16x8 __attribute__((ext_vector_type(8)));
typedef float f32x4 __attribute__((ext_vector_type(4)));
typedef unsigned short u16;
typedef unsigned int u32;

__device__ __forceinline__ float truncbf(float f) {
  u32 x = __builtin_bit_cast(u32, f) & 0xFFFF0000u;
  return __builtin_bit_cast(float, x);
}
// {hi16(b), hi16(a)} -> (bf(b)<<16)|bf(a)
__device__ __forceinline__ u32 packbf(float a, float b) {
  return __builtin_amdgcn_perm(__builtin_bit_cast(u32, b),
                               __builtin_bit_cast(u32, a), 0x07060302u);
}

__device__ __forceinline__ void async_ld16(const void* g, void* l) {
  __builtin_amdgcn_global_load_lds((const __attribute__((address_space(1))) u32*)g,
                                   (__attribute__((address_space(3))) u32*)l,
                                   16, 0, 0);
}

// ---------------------------------------------------------------------------
// Kernel 1: partial Gram over 256-row slices + colsum + (optional) xb emit.
// 256 blocks x 512 thr -> 1 block/CU, full GPU.
// ---------------------------------------------------------------------------
template <bool EMIT_XB>
__global__ __launch_bounds__(512, 2) void gram_partial(const float* __restrict__ x,
                                                       float* __restrict__ part,
                                                       float* __restrict__ colsum,
                                                       u32* __restrict__ xb) {
  __shared__ u32 xT[256 * 18];        // 18KB: ch-major, row-pairs packed
  __shared__ float cs_s[4][256];
  const int tid = threadIdx.x, lane = tid & 63;
  const int w = tid >> 6;
  const int wm = w >> 2, wn = w & 3;  // wave tile: 128(m) x 64(n) of G
  const int q = lane >> 4, r = lane & 15;
  const int row0 = blockIdx.x * 256;
  const int cpair = tid & 127, c0 = cpair * 2;
  const int npb = tid >> 7;           // 0..3

  f32x4 acc[8][4];
  #pragma unroll
  for (int i = 0; i < 8; ++i)
    #pragma unroll
    for (int j = 0; j < 4; ++j) acc[i][j] = (f32x4){0.f, 0.f, 0.f, 0.f};
  float cs0 = 0.f, cs1 = 0.f;

  for (int ch = 0; ch < 8; ++ch) {
    const int r0 = row0 + ch * 32;
    #pragma unroll
    for (int i = 0; i < 4; ++i) {
      int np = npb + i * 4;           // 0..15 row-pairs
      int n0 = r0 + np * 2;
      float2 g0 = *(const float2*)&x[(size_t)n0 * CIN + c0];
      float2 g1 = *(const float2*)&x[(size_t)(n0 + 1) * CIN + c0];
      xT[18 * c0 + np] = packbf(g0.x, g1.x);
      xT[18 * (c0 + 1) + np] = packbf(g0.y, g1.y);
      if (EMIT_XB) {
        xb[(size_t)n0 * 128 + cpair] = packbf(g0.x, g0.y);
        xb[(size_t)(n0 + 1) * 128 + cpair] = packbf(g1.x, g1.y);
      }
      cs0 += truncbf(g0.x) + truncbf(g1.x);
      cs1 += truncbf(g0.y) + truncbf(g1.y);
    }
    __syncthreads();
    bf16x8 af[8], bfr[4];
    #pragma unroll
    for (int mt = 0; mt < 8; ++mt) {
      int c = wm * 128 + mt * 16 + r;
      union { u32 d[4]; bf16x8 v; } t;
      const u32* p = &xT[18 * c + 4 * q];
      t.d[0] = p[0]; t.d[1] = p[1]; t.d[2] = p[2]; t.d[3] = p[3];
      af[mt] = t.v;
    }
    #pragma unroll
    for (int nt = 0; nt < 4; ++nt) {
      int c = wn * 64 + nt * 16 + r;
      union { u32 d[4]; bf16x8 v; } t;
      const u32* p = &xT[18 * c + 4 * q];
      t.d[0] = p[0]; t.d[1] = p[1]; t.d[2] = p[2]; t.d[3] = p[3];
      bfr[nt] = t.v;
    }
    #pragma unroll
    for (int mt = 0; mt < 8; ++mt)
      #pragma unroll
      for (int nt = 0; nt < 4; ++nt)
        acc[mt][nt] = __builtin_amdgcn_mfma_f32_16x16x32_bf16(af[mt], bfr[nt], acc[mt][nt], 0, 0, 0);
    __syncthreads();
  }

  float* pb = part + (size_t)blockIdx.x * 65536;
  #pragma unroll
  for (int mt = 0; mt < 8; ++mt)
    #pragma unroll
    for (int nt = 0; nt < 4; ++nt)
      #pragma unroll
      for (int i = 0; i < 4; ++i) {
        int row = wm * 128 + mt * 16 + q * 4 + i;
        int col = wn * 64 + nt * 16 + r;
        pb[row * 256 + col] = acc[mt][nt][i];
      }

  cs_s[npb][c0] = cs0;
  cs_s[npb][c0 + 1] = cs1;
  __syncthreads();
  if (tid < 256)
    atomicAdd(&colsum[tid], cs_s[0][tid] + cs_s[1][tid] + cs_s[2][tid] + cs_s[3][tid]);
}

// ---------------------------------------------------------------------------
// Kernel 2: reduce 256 partial Grams -> G
// ---------------------------------------------------------------------------
__global__ void gram_reduce(const float* __restrict__ part, float* __restrict__ G) {
  int g = blockIdx.x * 256 + threadIdx.x;
  float s = 0.f;
  for (int b = 0; b < 256; ++b) s += part[(size_t)b * 65536 + g];
  G[g] = s;
}

// ---------------------------------------------------------------------------
// Kernel 3: BN scale/bias per channel d from quadratic form.
// ---------------------------------------------------------------------------
__global__ __launch_bounds__(256) void stats_kernel(const float* __restrict__ G,
                                                    const float* __restrict__ colsum,
                                                    const float* __restrict__ W,
                                                    const float* __restrict__ gamma,
                                                    const float* __restrict__ beta,
                                                    float* __restrict__ scale,
                                                    float* __restrict__ bias) {
  const int d = blockIdx.x;
  const int t = threadIdx.x;
  __shared__ float wv[256][8];
  __shared__ float rr[16];
  float wt[8];
  #pragma unroll
  for (int k = 0; k < 8; ++k) wt[k] = truncbf(W[((size_t)k * CIN + t) * COUT + d]);
  #pragma unroll
  for (int k = 0; k < 8; ++k) wv[t][k] = wt[k];
  __syncthreads();

  float q = 0.f;
  for (int j = 0; j < 256; ++j) {
    float g = G[j * 256 + t];
    float dot = 0.f;
    #pragma unroll
    for (int k = 0; k < 8; ++k) dot += wv[j][k] * wt[k];
    q += g * dot;
  }
  float wsum = 0.f;
  #pragma unroll
  for (int k = 0; k < 8; ++k) wsum += wt[k];
  float m = colsum[t] * wsum;

  #pragma unroll
  for (int off = 32; off; off >>= 1) {
    q += __shfl_down(q, off, 64);
    m += __shfl_down(m, off, 64);
  }
  int wid = t >> 6;
  if ((t & 63) == 0) { rr[wid] = q; rr[wid + 8] = m; }
  __syncthreads();
  if (t == 0) {
    float qt = rr[0] + rr[1] + rr[2] + rr[3];
    float mn = rr[8] + rr[9] + rr[10] + rr[11];
    const float invM = 1.f / 524288.f;
    float mean = mn * invM;
    float var = qt * invM - mean * mean;
    float s = gamma[d] * rsqrtf(var + 1e-5f);
    scale[d] = s;
    bias[d] = beta[d] - mean * s;
  }
}

// ---------------------------------------------------------------------------
// Kernel 4: W fp32 [k][c][d] -> Wt bf16 [(k*8+cb)][d][ci]
// ---------------------------------------------------------------------------
__global__ void wtrans_kernel(const float* __restrict__ W, u16* __restrict__ Wt) {
  __shared__ u16 tile[32][128];
  const int blk = blockIdx.x, t = threadIdx.x;
  const int k = blk >> 3, cb = blk & 7;
  #pragma unroll
  for (int i = 0; i < 4; ++i) {
    int u = t + i * 256;
    int ci = u >> 5, d4 = (u & 31) * 4;
    float4 f = *(const float4*)&W[((size_t)k * CIN + cb * 32 + ci) * COUT + d4];
    uint2 p; p.x = packbf(f.x, f.y); p.y = packbf(f.z, f.w);
    *(uint2*)&tile[ci][d4] = p;
  }
  __syncthreads();
  #pragma unroll
  for (int i = 0; i < 2; ++i) {
    int v = t + i * 256;
    int d = v >> 2, c0 = (v & 3) * 8;
    union { u16 s[8]; uint4 u4; } p;
    #pragma unroll
    for (int j = 0; j < 8; ++j) p.s[j] = tile[c0 + j][d];
    *(uint4*)&Wt[((size_t)blk * 128 + d) * 32 + c0] = p.u4;
  }
}

// ---------------------------------------------------------------------------
// Kernel 5 (main path): GEMM from bf16 xb, all 8 k-offsets per block.
// 512 blocks x 256 thr. A-tile 128x256 bf16 = 64KB LDS staged ONCE per block
// (16 global_load_lds w=16 per thread, single barrier). Per k: B frags
// double-buffered from L2-resident Wt, 128 MFMAs, direct register stores.
// x is fetched exactly once across the whole GEMM.
// ---------------------------------------------------------------------------
__global__ __launch_bounds__(256, 2) void gemm_xb(const u16* __restrict__ xb,
                                                  const u16* __restrict__ Wt,
                                                  const float* __restrict__ scale,
                                                  const float* __restrict__ bias,
                                                  float* __restrict__ out) {
  __shared__ u16 As[32768];           // 64KB: [cb][row][32] bf16
  const int tid = threadIdx.x, lane = tid & 63;
  const int w = tid >> 6, wr = w >> 1, wc = w & 1;
  const int q = lane >> 4, r = lane & 15;
  const int m0 = blockIdx.x * 128;

  #pragma unroll
  for (int i = 0; i < 16; ++i) {
    int u = tid + i * 256;            // 4096 units of 16B
    int cb = u >> 9, row = (u >> 2) & 127, seg = u & 3;
    const u16* g = xb + (size_t)(m0 + row) * CIN + cb * 32 + seg * 8;
    async_ld16(g, As + (size_t)u * 8);
  }

  float sv[4], bv[4];
  #pragma unroll
  for (int nt = 0; nt < 4; ++nt) {
    int col = wc * 64 + nt * 16 + r;
    sv[nt] = scale[col]; bv[nt] = bias[col];
  }

  const int boff = (wc * 64 + r) * 32 + q * 8;
  bf16x8 bcur[4], bnext[4];
  #pragma unroll
  for (int nt = 0; nt < 4; ++nt)
    bcur[nt] = *(const bf16x8*)&Wt[boff + nt * 512];

  __syncthreads();                    // drains the A staging too

  int j = 0;                          // j = k*8+cb
  for (int k = 0; k < 8; ++k) {
    f32x4 acc[4][4];
    #pragma unroll
    for (int i = 0; i < 4; ++i)
      #pragma unroll
      for (int jj = 0; jj < 4; ++jj) acc[i][jj] = (f32x4){0.f, 0.f, 0.f, 0.f};

    #pragma unroll
    for (int cb = 0; cb < 8; ++cb) {
      if (j < 63) {
        #pragma unroll
        for (int nt = 0; nt < 4; ++nt)
          bnext[nt] = *(const bf16x8*)&Wt[(size_t)(j + 1) * 4096 + boff + nt * 512];
      }
      bf16x8 af[4];
      #pragma unroll
      for (int mt = 0; mt < 4; ++mt)
        af[mt] = *(const bf16x8*)&As[((cb * 128) + wr * 64 + mt * 16 + r) * 32 + q * 8];
      #pragma unroll
      for (int mt = 0; mt < 4; ++mt)
        #pragma unroll
        for (int nt = 0; nt < 4; ++nt)
          acc[mt][nt] = __builtin_amdgcn_mfma_f32_16x16x32_bf16(af[mt], bcur[nt], acc[mt][nt], 0, 0, 0);
      if (j < 63) {
        #pragma unroll
        for (int nt = 0; nt < 4; ++nt) bcur[nt] = bnext[nt];
      }
      ++j;
    }

    const size_t obase = (size_t)k * N_ROWS + m0;
    #pragma unroll
    for (int mt = 0; mt < 4; ++mt)
      #pragma unroll
      for (int nt = 0; nt < 4; ++nt)
        #pragma unroll
        for (int i = 0; i < 4; ++i) {
          int grow = wr * 64 + mt * 16 + q * 4 + i;
          int col = wc * 64 + nt * 16 + r;
          float y = acc[mt][nt][i] * sv[nt] + bv[nt];
          y = y > 0.f ? y : 0.f;
          out[(obase + grow) * COUT + col] = y;
        }
  }
}

// ---------------------------------------------------------------------------
// Kernel 5 (fallback, round-2 proven): GEMM from fp32 x, one k per block.
// ---------------------------------------------------------------------------
__global__ __launch_bounds__(256, 2) void gemm_fp32(const float* __restrict__ x,
                                                    const u16* __restrict__ Wt,
                                                    const float* __restrict__ scale,
                                                    const float* __restrict__ bias,
                                                    float* __restrict__ out) {
  __shared__ float Asf[4096];
  const int tid = threadIdx.x, lane = tid & 63;
  const int w = tid >> 6, wr = w >> 1, wc = w & 1;
  const int q = lane >> 4, r = lane & 15;
  const int k = blockIdx.x & 7;
  const int m0 = (blockIdx.x >> 3) * 128;

  const u16* wbase = Wt + (size_t)k * 8 * 4096;
  const int boff = (wc * 64 + r) * 32 + q * 8;

  bf16x8 bcur[4], bnext[4];
  #pragma unroll
  for (int nt = 0; nt < 4; ++nt)
    bcur[nt] = *(const bf16x8*)&wbase[boff + nt * 512];

  f32x4 acc[4][4];
  #pragma unroll
  for (int i = 0; i < 4; ++i)
    #pragma unroll
    for (int j = 0; j < 4; ++j) acc[i][j] = (f32x4){0.f, 0.f, 0.f, 0.f};

  for (int cb = 0; cb < 8; ++cb) {
    #pragma unroll
    for (int i = 0; i < 4; ++i) {
      int u = tid + i * 256;
      int row = u >> 3;
      int s = (u & 7) ^ (row & 7);
      const float* g = x + (size_t)(m0 + row) * CIN + cb * 32 + s * 4;
      async_ld16(g, Asf + (w * 64 + i * 256) * 4);
    }
    if (cb < 7) {
      #pragma unroll
      for (int nt = 0; nt < 4; ++nt)
        bnext[nt] = *(const bf16x8*)&wbase[(cb + 1) * 4096 + boff + nt * 512];
    }
    __syncthreads();
    bf16x8 af[4];
    #pragma unroll
    for (int mt = 0; mt < 4; ++mt) {
      int row = wr * 64 + mt * 16 + r;
      union { u32 d[4]; bf16x8 v; } t;
      #pragma unroll
      for (int b = 0; b < 2; ++b) {
        int unit = row * 8 + ((2 * q + b) ^ (row & 7));
        float4 f = *(const float4*)&Asf[unit * 4];
        t.d[b * 2 + 0] = packbf(f.x, f.y);
        t.d[b * 2 + 1] = packbf(f.z, f.w);
      }
      af[mt] = t.v;
    }
    #pragma unroll
    for (int mt = 0; mt < 4; ++mt)
      #pragma unroll
      for (int nt = 0; nt < 4; ++nt)
        acc[mt][nt] = __builtin_amdgcn_mfma_f32_16x16x32_bf16(af[mt], bcur[nt], acc[mt][nt], 0, 0, 0);
    __syncthreads();
    if (cb < 7) {
      #pragma unroll
      for (int nt = 0; nt < 4; ++nt) bcur[nt] = bnext[nt];
    }
  }

  float sv[4], bv[4];
  #pragma unroll
  for (int nt = 0; nt < 4; ++nt) {
    int col = wc * 64 + nt * 16 + r;
    sv[nt] = scale[col]; bv[nt] = bias[col];
  }
  const size_t obase = (size_t)k * N_ROWS + m0;
  #pragma unroll
  for (int mt = 0; mt < 4; ++mt)
    #pragma unroll
    for (int nt = 0; nt < 4; ++nt)
      #pragma unroll
      for (int i = 0; i < 4; ++i) {
        int grow = wr * 64 + mt * 16 + q * 4 + i;
        int col = wc * 64 + nt * 16 + r;
        float y = acc[mt][nt][i] * sv[nt] + bv[nt];
        y = y > 0.f ? y : 0.f;
        out[(obase + grow) * COUT + col] = y;
      }
}

extern "C" void kernel_launch(void* const* d_in, const int* in_sizes, int n_in,
                              void* d_out, int out_size, void* d_ws, size_t ws_size,
                              hipStream_t stream) {
  const float* x = (const float*)d_in[0];
  const float* W = (const float*)d_in[1];
  const float* gamma = (const float*)d_in[2];
  const float* beta = (const float*)d_in[3];
  float* out = (float*)d_out;

  float* ws = (float*)d_ws;
  float* G = ws;                       // 65536 f32
  float* colsum = ws + 65536;          // 256
  float* scale = ws + 65792;           // 128
  float* bias = ws + 65920;            // 128
  u16* Wt = (u16*)(ws + 66048);        // 512KB bf16
  u32* xb = (u32*)((char*)d_ws + (1 << 20));   // 32MB bf16-pairs at +1MB
  const size_t need = (1u << 20) + (size_t)N_ROWS * CIN * 2;
  const bool big_ws = ws_size >= need;

  // Gram partials staged in d_out (64MB of 256MB) — fully overwritten by gemm.
  float* part = (float*)d_out;

  hipMemsetAsync(colsum, 0, 256 * sizeof(float), stream);
  if (big_ws) {
    gram_partial<true><<<256, 512, 0, stream>>>(x, part, colsum, xb);
  } else {
    gram_partial<false><<<256, 512, 0, stream>>>(x, part, colsum, xb);
  }
  gram_reduce<<<256, 256, 0, stream>>>(part, G);
  stats_kernel<<<128, 256, 0, stream>>>(G, colsum, W, gamma, beta, scale, bias);
  wtrans_kernel<<<64, 256, 0, stream>>>(W, Wt);
  if (big_ws) {
    gemm_xb<<<512, 256, 0, stream>>>((const u16*)xb, Wt, scale, bias, out);
  } else {
    gemm_fp32<<<4096, 256, 0, stream>>>(x, Wt, scale, bias, out);
  }
}